// Round 4
// baseline (736.382 us; speedup 1.0000x reference)
//
#include <hip/hip_runtime.h>

typedef float v2f __attribute__((ext_vector_type(2)));

#define HH 512
#define WW 512
#define NPLANES 96
#define BLOCK 256
#define ROWS_PB 64
#define ROW_TILES 8           // 512 / 64
#define HALO 5
#define KW 11
#define NS 13                 // LDS ring slots (== register ring depth)
#define SLOT_F 1152           // floats/slot: x[0,528) pad[528,576) y[576,1104) pad[1104,1152)
#define YOFF 576
#define LDSW 528              // padded row width; LDS col 0 <-> global col -8
#define PADL 8
#define NOUT 64               // output rows per tile

#define C1V 1e-4f
#define C2V 9e-4f
#define EPSV 1e-8f
#define NPIX 25165824.0f      // 32*3*512*512
#define NBLK (ROW_TILES * NPLANES)   // 768

// per-thread ring: h-blurred rows, 13 slots x 5 quantities x 2 cols
struct Rings { v2f hx[NS], hy[NS], hx2[NS], hy2[NS], hxy[NS]; };

__device__ __forceinline__ void gld16(const float* g, float* l) {
  __builtin_amdgcn_global_load_lds((const __attribute__((address_space(1))) void*)g,
                                   (__attribute__((address_space(3))) void*)l, 16, 0, 0);
}
__device__ __forceinline__ void gld4(const float* g, float* l) {
  __builtin_amdgcn_global_load_lds((const __attribute__((address_space(1))) void*)g,
                                   (__attribute__((address_space(3))) void*)l, 4, 0, 0);
}

// Issue the 6 DMA instrs staging one row-pair (x row + y row, padded) into a slot.
// cb/csB: per-lane chunk descriptors (base ptr incl. column, byte row-stride 0|2048).
__device__ __forceinline__ void dma_slot(float* slotBase,
                                         const float* const* cb, const int* csB,
                                         int ri, const float* zp)
{
  const bool rok = ((unsigned)ri) < (unsigned)HH;
  const int rr = rok ? ri : 0;
  #pragma unroll
  for (int q = 0; q < 4; ++q) {
    uintptr_t a = (uintptr_t)cb[q] + (unsigned)(rr * csB[q]);
    if (!rok) a = (uintptr_t)zp;
    gld16((const float*)a, slotBase + 256 * q);
  }
  #pragma unroll
  for (int q = 4; q < 6; ++q) {
    uintptr_t a = (uintptr_t)cb[q] + (unsigned)(rr * csB[q]);
    if (!rok) a = (uintptr_t)zp;
    gld4((const float*)a, slotBase + 1024 + 64 * (q - 4));
  }
}

// horizontal 11-tap blur of thread t's 2-column pair from LDS slot S -> ring slot S
template <int S>
__device__ __forceinline__ void hblur_slot(Rings& rg, float (*lds)[SLOT_F],
                                           const float* wv, int t)
{
  const v2f* xb = (const v2f*)&lds[S][0];
  const v2f* yb = (const v2f*)&lds[S][YOFF];
  v2f X[7], Y[7];
  #pragma unroll
  for (int j = 0; j < 7; ++j) { X[j] = xb[t + 1 + j]; Y[j] = yb[t + 1 + j]; }

  v2f hx = {0.f,0.f}, hy = {0.f,0.f}, hx2 = {0.f,0.f}, hy2 = {0.f,0.f}, hxy = {0.f,0.f};
  #pragma unroll
  for (int k = 0; k < KW; ++k) {
    v2f xt, yt;
    if (k & 1) { xt = X[(k + 1) >> 1]; yt = Y[(k + 1) >> 1]; }
    else {
      xt.x = X[k >> 1].y; xt.y = X[(k >> 1) + 1].x;
      yt.x = Y[k >> 1].y; yt.y = Y[(k >> 1) + 1].x;
    }
    const float w = wv[k];
    const v2f tt = w * xt, uu = w * yt;
    hx += tt; hy += uu;
    hx2 = __builtin_elementwise_fma(tt, xt, hx2);
    hy2 = __builtin_elementwise_fma(uu, yt, hy2);
    hxy = __builtin_elementwise_fma(tt, yt, hxy);
  }
  rg.hx[S] = hx; rg.hy[S] = hy; rg.hx2[S] = hx2; rg.hy2[S] = hy2; rg.hxy[S] = hxy;
}

// phase r (P = r % 13): wait DMA(row r+5), barrier, DMA row r+7, hblur row r+5,
// vertical blur rows r-5..r+5 (ring slots (P+j)%13), SSIM epilogue.
template <int P>
__device__ __forceinline__ void phase_step(Rings& rg, float (*lds)[SLOT_F],
                                           const float* wv, int t, int wid, v2f& acc,
                                           const float* const* cb, const int* csB,
                                           int r, int R0, const float* zp)
{
  asm volatile("s_waitcnt vmcnt(6)" ::: "memory");
  __builtin_amdgcn_s_barrier();
  if (wid == 0) {
    constexpr int SD = (P + 12) % NS;          // slot of row r-6 (retired)
    dma_slot(&lds[SD][0], cb, csB, R0 + r + 7, zp);
  }
  if (r < NOUT) {
    constexpr int SN = (P + 10) % NS;          // slot & ring index of row r+5
    hblur_slot<SN>(rg, lds, wv, t);

    v2f mx = {0.f,0.f}, my = {0.f,0.f}, ex2 = {0.f,0.f}, ey2 = {0.f,0.f}, exy = {0.f,0.f};
    #pragma unroll
    for (int k = 0; k < KW; ++k) {
      const int s = (P + k) % NS;              // constant after unroll
      const float w = wv[k];
      mx  = __builtin_elementwise_fma((v2f)(w), rg.hx[s],  mx);
      my  = __builtin_elementwise_fma((v2f)(w), rg.hy[s],  my);
      ex2 = __builtin_elementwise_fma((v2f)(w), rg.hx2[s], ex2);
      ey2 = __builtin_elementwise_fma((v2f)(w), rg.hy2[s], ey2);
      exy = __builtin_elementwise_fma((v2f)(w), rg.hxy[s], exy);
    }
    const v2f mx2 = mx * mx, my2 = my * my, mxy = mx * my;
    const v2f sx2 = ex2 - mx2, sy2 = ey2 - my2, sxy = exy - mxy;
    const v2f num = (2.f * mxy + C1V) * (2.f * sxy + C2V);
    const v2f den = (mx2 + my2 + C1V) * (sx2 + sy2 + C2V) + EPSV;
    v2f rc;
    rc.x = __builtin_amdgcn_rcpf(den.x);
    rc.y = __builtin_amdgcn_rcpf(den.y);
    acc = __builtin_elementwise_fma(num, rc, acc);
  }
}

__global__ __launch_bounds__(BLOCK, 2) void ssim_main(const float* __restrict__ x,
                                                      const float* __restrict__ y,
                                                      float* __restrict__ ws)
{
  __shared__ float lds[NS][SLOT_F];
  __shared__ float wsum[4];

  const int t = threadIdx.x;
  const int wid = t >> 6;
  const int lane = t & 63;
  const int rowT = blockIdx.x;
  const int plane = blockIdx.y;
  const int R0 = rowT * ROWS_PB;

  const float* xp = x + (ptrdiff_t)plane * (HH * WW);
  const float* yp = y + (ptrdiff_t)plane * (HH * WW);
  const float* zp = ws;                      // 256-float zero page (zeroed each launch)
  float* partial = ws + 256;

  // Gaussian window (exact reference formula), hoisted to SGPRs.
  float wv[KW];
  {
    float s = 0.f;
    #pragma unroll
    for (int k = 0; k < KW; ++k) {
      const float d = (float)(k - HALO);
      wv[k] = expf(-(d * d) / 4.5f);         // 2*sigma^2 = 4.5
      s += wv[k];
    }
    const float inv = 1.f / s;
    #pragma unroll
    for (int k = 0; k < KW; ++k) {
      wv[k] *= inv;
      wv[k] = __int_as_float(__builtin_amdgcn_readfirstlane(__float_as_int(wv[k])));
    }
  }

  // per-lane DMA chunk descriptors: slot float-offset -> (array, global col)
  const float* cb[6];
  int csB[6];
  #pragma unroll
  for (int q = 0; q < 6; ++q) {
    const int o = (q < 4) ? (256 * q + 4 * lane) : (1024 + 64 * (q - 4) + lane);
    const int arr = (o >= YOFF) ? 1 : 0;
    const int col = o - (arr ? YOFF : 0);
    const int gc = col - PADL;
    const bool valid = (col < LDSW) && (gc >= 0) && (gc < WW);
    cb[q] = valid ? ((arr ? yp : xp) + gc) : zp;
    csB[q] = valid ? (WW * 4) : 0;
  }

  Rings rg;
  v2f acc = {0.f, 0.f};

  // prologue: DMA rows R0-5..R0+6 into slots 0..11
  if (wid == 0) {
    for (int s = 0; s < 12; ++s)
      dma_slot(&lds[s][0], cb, csB, R0 - HALO + s, zp);
  }
  asm volatile("s_waitcnt vmcnt(12)" ::: "memory");   // rows R0-5..R0+4 landed
  __builtin_amdgcn_s_barrier();

  // ring fill: h-blur rows R0-5..R0+4 (slots 0..9)
  hblur_slot<0>(rg, lds, wv, t);
  hblur_slot<1>(rg, lds, wv, t);
  hblur_slot<2>(rg, lds, wv, t);
  hblur_slot<3>(rg, lds, wv, t);
  hblur_slot<4>(rg, lds, wv, t);
  hblur_slot<5>(rg, lds, wv, t);
  hblur_slot<6>(rg, lds, wv, t);
  hblur_slot<7>(rg, lds, wv, t);
  hblur_slot<8>(rg, lds, wv, t);
  hblur_slot<9>(rg, lds, wv, t);

  // 5 groups x 13 phases = 65 (phase 64 gated: DMA/wait only, keeps vmcnt uniform)
  #pragma unroll 1
  for (int g = 0; g < 5; ++g) {
    const int rb = 13 * g;
    phase_step<0 >(rg, lds, wv, t, wid, acc, cb, csB, rb + 0 , R0, zp);
    phase_step<1 >(rg, lds, wv, t, wid, acc, cb, csB, rb + 1 , R0, zp);
    phase_step<2 >(rg, lds, wv, t, wid, acc, cb, csB, rb + 2 , R0, zp);
    phase_step<3 >(rg, lds, wv, t, wid, acc, cb, csB, rb + 3 , R0, zp);
    phase_step<4 >(rg, lds, wv, t, wid, acc, cb, csB, rb + 4 , R0, zp);
    phase_step<5 >(rg, lds, wv, t, wid, acc, cb, csB, rb + 5 , R0, zp);
    phase_step<6 >(rg, lds, wv, t, wid, acc, cb, csB, rb + 6 , R0, zp);
    phase_step<7 >(rg, lds, wv, t, wid, acc, cb, csB, rb + 7 , R0, zp);
    phase_step<8 >(rg, lds, wv, t, wid, acc, cb, csB, rb + 8 , R0, zp);
    phase_step<9 >(rg, lds, wv, t, wid, acc, cb, csB, rb + 9 , R0, zp);
    phase_step<10>(rg, lds, wv, t, wid, acc, cb, csB, rb + 10, R0, zp);
    phase_step<11>(rg, lds, wv, t, wid, acc, cb, csB, rb + 11, R0, zp);
    phase_step<12>(rg, lds, wv, t, wid, acc, cb, csB, rb + 12, R0, zp);
  }

  // block reduction; __syncthreads drains wave0's outstanding DMA (vmcnt 0)
  float a = acc.x + acc.y;
  #pragma unroll
  for (int off = 32; off > 0; off >>= 1) a += __shfl_down(a, off);
  __syncthreads();
  if (lane == 0) wsum[wid] = a;
  __syncthreads();
  if (t == 0) partial[plane * ROW_TILES + rowT] = wsum[0] + wsum[1] + wsum[2] + wsum[3];
}

__global__ void zero_ws_kernel(float* __restrict__ ws)
{
  ws[threadIdx.x] = 0.f;   // 256-float zero page
}

__global__ void finalize_kernel(const float* __restrict__ partial, float* __restrict__ out)
{
  __shared__ float s4[4];
  float a = 0.f;
  for (int i = threadIdx.x; i < NBLK; i += 256) a += partial[i];
  #pragma unroll
  for (int off = 32; off > 0; off >>= 1) a += __shfl_down(a, off);
  if ((threadIdx.x & 63) == 0) s4[threadIdx.x >> 6] = a;
  __syncthreads();
  if (threadIdx.x == 0) out[0] = 1.f - (s4[0] + s4[1] + s4[2] + s4[3]) * (1.f / NPIX);
}

extern "C" void kernel_launch(void* const* d_in, const int* in_sizes, int n_in,
                              void* d_out, int out_size, void* d_ws, size_t ws_size,
                              hipStream_t stream)
{
  const float* x = (const float*)d_in[0];
  const float* y = (const float*)d_in[1];
  float* ws = (float*)d_ws;
  float* out = (float*)d_out;

  hipLaunchKernelGGL(zero_ws_kernel, dim3(1), dim3(256), 0, stream, ws);
  hipLaunchKernelGGL(ssim_main, dim3(ROW_TILES, NPLANES), dim3(BLOCK), 0, stream, x, y, ws);
  hipLaunchKernelGGL(finalize_kernel, dim3(1), dim3(256), 0, stream, ws + 256, out);
}

// Round 5
// 601.328 us; speedup vs baseline: 1.2246x; 1.2246x over previous
//
#include <hip/hip_runtime.h>

typedef float v2f __attribute__((ext_vector_type(2)));

#define HH 512
#define WW 512
#define NPLANES 96
#define BLOCK 64          // 1 wave per block -> no barriers needed at all
#define COLS_PB 128       // 64 threads x 2 columns
#define ROWS_PB 64
#define COL_TILES 4       // 512 / 128
#define ROW_TILES 8       // 512 / 64
#define HALO 5
#define KW 11
#define NS 11             // LDS raw-row ring slots == register ring depth
#define SLOT_F 288        // floats/slot: x[0,144) y[144,288)  (1152 B)
#define YOFF 144
#define PADL 8            // LDS float i <-> global col C0-8+i
#define NCHUNK 36         // 16B chunks per padded 144-float row
#define NOUT 64

#define C1V 1e-4f
#define C2V 9e-4f
#define EPSV 1e-8f
#define NPIX 25165824.0f  // 32*3*512*512
#define NBLK (COL_TILES * ROW_TILES * NPLANES)   // 3072

// per-thread ring: h-blurred rows, 11 slots x 5 quantities x 2 cols (110 VGPR)
struct Rings { v2f hx[NS], hy[NS], hx2[NS], hy2[NS], hxy[NS]; };

__device__ __forceinline__ void gld16(const float* g, float* l) {
  __builtin_amdgcn_global_load_lds((const __attribute__((address_space(1))) void*)g,
                                   (__attribute__((address_space(3))) void*)l, 16, 0, 0);
}

// clamped per-lane source address for one row (zero page if out of image)
__device__ __forceinline__ const float* rowaddr(const float* pCol, int row,
                                                bool colOK, const float* zp)
{
  const float* a = pCol + (ptrdiff_t)row * WW;
  return (colOK && ((unsigned)row < (unsigned)HH)) ? a : zp;
}

// stage one row-pair into LDS slot: 2 DMA instructions, zero VGPR data movement
__device__ __forceinline__ void dma_row(float* slotBase, const float* ax,
                                        const float* ay, int t)
{
  if (t < NCHUNK) {
    gld16(ax, slotBase);
    gld16(ay, slotBase + YOFF);
  }
}

// horizontal 11-tap blur of thread t's 2-column pair from LDS slot S -> ring slot S
template <int S>
__device__ __forceinline__ void hblur_slot(Rings& rg, float (*lds)[SLOT_F],
                                           const float* wv, int t)
{
  const v2f* xb = (const v2f*)&lds[S][0];
  const v2f* yb = (const v2f*)&lds[S][YOFF];
  v2f X[7], Y[7];
  #pragma unroll
  for (int j = 0; j < 7; ++j) { X[j] = xb[t + 1 + j]; Y[j] = yb[t + 1 + j]; }

  v2f hx = {0.f,0.f}, hy = {0.f,0.f}, hx2 = {0.f,0.f}, hy2 = {0.f,0.f}, hxy = {0.f,0.f};
  #pragma unroll
  for (int k = 0; k < KW; ++k) {
    v2f xt, yt;
    if (k & 1) { xt = X[(k + 1) >> 1]; yt = Y[(k + 1) >> 1]; }
    else {
      xt.x = X[k >> 1].y; xt.y = X[(k >> 1) + 1].x;
      yt.x = Y[k >> 1].y; yt.y = Y[(k >> 1) + 1].x;
    }
    const float w = wv[k];
    const v2f tt = w * xt, uu = w * yt;
    hx += tt; hy += uu;
    hx2 = __builtin_elementwise_fma(tt, xt, hx2);
    hy2 = __builtin_elementwise_fma(uu, yt, hy2);
    hxy = __builtin_elementwise_fma(tt, yt, hxy);
  }
  rg.hx[S] = hx; rg.hy[S] = hy; rg.hx2[S] = hx2; rg.hy2[S] = hy2; rg.hxy[S] = hxy;
}

// phase q (P = q%11): issue DMA row R0+7+q into slot (P+1)%11, wait vmcnt(4)
// (rows q+6, q+7 = 4 instrs may stay in flight -> row q+5 has landed),
// h-blur row R0+5+q from slot (P+10)%11, vertical blur + SSIM epilogue.
template <int P>
__device__ __forceinline__ void phase_step(Rings& rg, float (*lds)[SLOT_F],
                                           const float* wv, int t, v2f& acc,
                                           const float* pX, const float* pY,
                                           bool colOK, const float* zp,
                                           int q, int R0, bool live)
{
  {
    const int row = R0 + 7 + q;
    const float* ax = rowaddr(pX, row, colOK, zp);
    const float* ay = rowaddr(pY, row, colOK, zp);
    dma_row(&lds[(P + 1) % NS][0], ax, ay, t);
  }
  asm volatile("s_waitcnt vmcnt(4)" ::: "memory");

  if (live) {
    constexpr int SN = (P + 10) % NS;
    hblur_slot<SN>(rg, lds, wv, t);

    v2f mx = {0.f,0.f}, my = {0.f,0.f}, ex2 = {0.f,0.f}, ey2 = {0.f,0.f}, exy = {0.f,0.f};
    #pragma unroll
    for (int k = 0; k < KW; ++k) {
      const int s = (P + k) % NS;   // constant after unroll
      const float w = wv[k];
      mx  = __builtin_elementwise_fma((v2f)(w), rg.hx[s],  mx);
      my  = __builtin_elementwise_fma((v2f)(w), rg.hy[s],  my);
      ex2 = __builtin_elementwise_fma((v2f)(w), rg.hx2[s], ex2);
      ey2 = __builtin_elementwise_fma((v2f)(w), rg.hy2[s], ey2);
      exy = __builtin_elementwise_fma((v2f)(w), rg.hxy[s], exy);
    }
    const v2f mx2 = mx * mx, my2 = my * my, mxy = mx * my;
    const v2f sx2 = ex2 - mx2, sy2 = ey2 - my2, sxy = exy - mxy;
    const v2f num = (2.f * mxy + C1V) * (2.f * sxy + C2V);
    const v2f den = (mx2 + my2 + C1V) * (sx2 + sy2 + C2V) + EPSV;
    v2f rc;
    rc.x = __builtin_amdgcn_rcpf(den.x);
    rc.y = __builtin_amdgcn_rcpf(den.y);
    acc = __builtin_elementwise_fma(num, rc, acc);
  }
}

__global__ __launch_bounds__(BLOCK)
__attribute__((amdgpu_waves_per_eu(2, 3)))
void ssim_main(const float* __restrict__ x, const float* __restrict__ y,
               float* __restrict__ ws)
{
  __shared__ float lds[NS][SLOT_F];   // 12.7 KB

  const int t = threadIdx.x;
  const int colT = blockIdx.x & (COL_TILES - 1);
  const int rowT = blockIdx.x >> 2;
  const int plane = blockIdx.y;
  const int C0 = colT * COLS_PB;
  const int R0 = rowT * ROWS_PB;

  const float* xp = x + (ptrdiff_t)plane * (HH * WW);
  const float* yp = y + (ptrdiff_t)plane * (HH * WW);
  const float* zp = ws;                       // 256-float zero page
  float* partial = ws + 256;

  // Gaussian window (exact reference formula), hoisted to SGPRs.
  float wv[KW];
  {
    float s = 0.f;
    #pragma unroll
    for (int k = 0; k < KW; ++k) {
      const float d = (float)(k - HALO);
      wv[k] = expf(-(d * d) / 4.5f);          // 2*sigma^2 = 4.5
      s += wv[k];
    }
    const float inv = 1.f / s;
    #pragma unroll
    for (int k = 0; k < KW; ++k) {
      wv[k] *= inv;
      wv[k] = __int_as_float(__builtin_amdgcn_readfirstlane(__float_as_int(wv[k])));
    }
  }

  // per-lane column descriptors (named scalars, no arrays -> no stack)
  const int gc = C0 - PADL + 4 * t;           // first col of this lane's 16B chunk
  const bool colOK = (gc >= 0) && (gc + 3 < WW);
  const float* pX = xp + gc;
  const float* pY = yp + gc;

  Rings rg;
  v2f acc = {0.f, 0.f};

  // prologue: DMA rows R0-5..R0+5 into slots 0..10 (22 instrs)
  for (int s = 0; s < NS; ++s) {
    const int row = R0 - HALO + s;
    dma_row(&lds[s][0], rowaddr(pX, row, colOK, zp), rowaddr(pY, row, colOK, zp), t);
  }
  asm volatile("s_waitcnt vmcnt(2)" ::: "memory");   // rows R0-5..R0+4 landed

  // ring fill: h-blur rows R0-5..R0+4 (slots 0..9)
  hblur_slot<0>(rg, lds, wv, t);
  hblur_slot<1>(rg, lds, wv, t);
  hblur_slot<2>(rg, lds, wv, t);
  hblur_slot<3>(rg, lds, wv, t);
  hblur_slot<4>(rg, lds, wv, t);
  hblur_slot<5>(rg, lds, wv, t);
  hblur_slot<6>(rg, lds, wv, t);
  hblur_slot<7>(rg, lds, wv, t);
  hblur_slot<8>(rg, lds, wv, t);
  hblur_slot<9>(rg, lds, wv, t);

  // slot 0 (row R0-5) is consumed; refill with row R0+6 (needed at phase q=1)
  dma_row(&lds[0][0], rowaddr(pX, R0 + 6, colOK, zp), rowaddr(pY, R0 + 6, colOK, zp), t);

  // main: 6 groups x 11 phases; q = 11g+P; live output rows are q < 64
  #pragma unroll 1
  for (int g = 0; g < 6; ++g) {
    const int qb = 11 * g;
    phase_step<0 >(rg, lds, wv, t, acc, pX, pY, colOK, zp, qb + 0 , R0, qb + 0  < NOUT);
    phase_step<1 >(rg, lds, wv, t, acc, pX, pY, colOK, zp, qb + 1 , R0, qb + 1  < NOUT);
    phase_step<2 >(rg, lds, wv, t, acc, pX, pY, colOK, zp, qb + 2 , R0, qb + 2  < NOUT);
    phase_step<3 >(rg, lds, wv, t, acc, pX, pY, colOK, zp, qb + 3 , R0, qb + 3  < NOUT);
    phase_step<4 >(rg, lds, wv, t, acc, pX, pY, colOK, zp, qb + 4 , R0, qb + 4  < NOUT);
    phase_step<5 >(rg, lds, wv, t, acc, pX, pY, colOK, zp, qb + 5 , R0, qb + 5  < NOUT);
    phase_step<6 >(rg, lds, wv, t, acc, pX, pY, colOK, zp, qb + 6 , R0, qb + 6  < NOUT);
    phase_step<7 >(rg, lds, wv, t, acc, pX, pY, colOK, zp, qb + 7 , R0, qb + 7  < NOUT);
    phase_step<8 >(rg, lds, wv, t, acc, pX, pY, colOK, zp, qb + 8 , R0, qb + 8  < NOUT);
    phase_step<9 >(rg, lds, wv, t, acc, pX, pY, colOK, zp, qb + 9 , R0, qb + 9  < NOUT);
    phase_step<10>(rg, lds, wv, t, acc, pX, pY, colOK, zp, qb + 10, R0, qb + 10 < NOUT);
  }

  // drain outstanding DMA before LDS goes away
  asm volatile("s_waitcnt vmcnt(0)" ::: "memory");

  // single-wave shuffle reduction -> deterministic per-block partial
  float a = acc.x + acc.y;
  #pragma unroll
  for (int off = 32; off > 0; off >>= 1) a += __shfl_down(a, off);
  if (t == 0) partial[blockIdx.y * (COL_TILES * ROW_TILES) + blockIdx.x] = a;
}

__global__ void zero_ws_kernel(float* __restrict__ ws)
{
  ws[threadIdx.x] = 0.f;   // zero page (needs >= 144 floats)
}

__global__ void finalize_kernel(const float* __restrict__ partial, float* __restrict__ out)
{
  __shared__ float s4[4];
  float a = 0.f;
  for (int i = threadIdx.x; i < NBLK; i += 256) a += partial[i];
  #pragma unroll
  for (int off = 32; off > 0; off >>= 1) a += __shfl_down(a, off);
  if ((threadIdx.x & 63) == 0) s4[threadIdx.x >> 6] = a;
  __syncthreads();
  if (threadIdx.x == 0) out[0] = 1.f - (s4[0] + s4[1] + s4[2] + s4[3]) * (1.f / NPIX);
}

extern "C" void kernel_launch(void* const* d_in, const int* in_sizes, int n_in,
                              void* d_out, int out_size, void* d_ws, size_t ws_size,
                              hipStream_t stream)
{
  const float* x = (const float*)d_in[0];
  const float* y = (const float*)d_in[1];
  float* ws = (float*)d_ws;
  float* out = (float*)d_out;

  hipLaunchKernelGGL(zero_ws_kernel, dim3(1), dim3(256), 0, stream, ws);
  hipLaunchKernelGGL(ssim_main, dim3(COL_TILES * ROW_TILES, NPLANES), dim3(BLOCK),
                     0, stream, x, y, ws);
  hipLaunchKernelGGL(finalize_kernel, dim3(1), dim3(256), 0, stream, ws + 256, out);
}

// Round 6
// 491.351 us; speedup vs baseline: 1.4987x; 1.2238x over previous
//
#include <hip/hip_runtime.h>

typedef float v2f __attribute__((ext_vector_type(2)));

#define HH 512
#define WW 512
#define NPLANES 96
#define BLOCK 64          // 1 wave per block -> no barriers anywhere
#define COLS_PB 128       // 64 threads x 2 columns
#define ROWS_PB 64
#define COL_TILES 4       // 512 / 128
#define ROW_TILES 8       // 512 / 64
#define HALO 5
#define NS 11             // LDS raw-row ring slots == named register ring depth
#define SLOT_F 288        // floats/slot: x[0,144) y[144,288)
#define YOFF 144
#define PADL 8            // LDS float i <-> global col C0-8+i
#define NCHUNK 36         // 16B chunks per padded 144-float row
#define NOUT 64

#define C1V 1e-4f
#define C2V 9e-4f
#define EPSV 1e-8f
#define NPIX 25165824.0f  // 32*3*512*512
#define NBLK (COL_TILES * ROW_TILES * NPLANES)   // 3072

#define FMA2(a,b,c) __builtin_elementwise_fma((a),(b),(c))

__device__ __forceinline__ void gld16(const float* g, float* l) {
  __builtin_amdgcn_global_load_lds((const __attribute__((address_space(1))) void*)g,
                                   (__attribute__((address_space(3))) void*)l, 16, 0, 0);
}

__device__ __forceinline__ const float* rowaddr(const float* pCol, int row,
                                                bool colOK, const float* zp)
{
  const float* a = pCol + (ptrdiff_t)row * WW;
  return (colOK && ((unsigned)row < (unsigned)HH)) ? a : zp;
}

// one row-pair -> LDS slot: 2 DMA instrs, zero VGPR data movement
__device__ __forceinline__ void dma_row(float* slotBase, const float* ax,
                                        const float* ay, int t)
{
  if (t < NCHUNK) {
    gld16(ax, slotBase);
    gld16(ay, slotBase + YOFF);
  }
}

// ---- macros: every ring/weight/tap value is a NAMED variable (no arrays, so
// SROA never sees a variable index -> nothing can fall to scratch) ----

#define TAP(W, AX, AY) { const v2f ax_ = (AX), ay_ = (AY); \
  const v2f tt_ = (W) * ax_, uu_ = (W) * ay_; \
  shx += tt_; shy += uu_; \
  shx2 = FMA2(tt_, ax_, shx2); shy2 = FMA2(uu_, ay_, shy2); shxy = FMA2(tt_, ay_, shxy); }

#define HBLUR(S) { \
  const v2f* xb_ = (const v2f*)&lds[S][0]; \
  const v2f* yb_ = (const v2f*)&lds[S][YOFF]; \
  const v2f X0 = xb_[t+1], X1 = xb_[t+2], X2 = xb_[t+3], X3 = xb_[t+4]; \
  const v2f X4 = xb_[t+5], X5 = xb_[t+6], X6 = xb_[t+7]; \
  const v2f Y0 = yb_[t+1], Y1 = yb_[t+2], Y2 = yb_[t+3], Y3 = yb_[t+4]; \
  const v2f Y4 = yb_[t+5], Y5 = yb_[t+6], Y6 = yb_[t+7]; \
  v2f shx = {0.f,0.f}, shy = {0.f,0.f}, shx2 = {0.f,0.f}, shy2 = {0.f,0.f}, shxy = {0.f,0.f}; \
  TAP(wv0,  ((v2f){X0.y, X1.x}), ((v2f){Y0.y, Y1.x})) \
  TAP(wv1,  X1,                  Y1) \
  TAP(wv2,  ((v2f){X1.y, X2.x}), ((v2f){Y1.y, Y2.x})) \
  TAP(wv3,  X2,                  Y2) \
  TAP(wv4,  ((v2f){X2.y, X3.x}), ((v2f){Y2.y, Y3.x})) \
  TAP(wv5,  X3,                  Y3) \
  TAP(wv6,  ((v2f){X3.y, X4.x}), ((v2f){Y3.y, Y4.x})) \
  TAP(wv7,  X4,                  Y4) \
  TAP(wv8,  ((v2f){X4.y, X5.x}), ((v2f){Y4.y, Y5.x})) \
  TAP(wv9,  X5,                  Y5) \
  TAP(wv10, ((v2f){X5.y, X6.x}), ((v2f){Y5.y, Y6.x})) \
  hx##S = shx; hy##S = shy; hx2_##S = shx2; hy2_##S = shy2; hxy##S = shxy; }

#define VSUM(res, pfx, a0,a1,a2,a3,a4,a5,a6,a7,a8,a9,a10) \
  res = ((v2f)(wv0)) * pfx##a0; \
  res = FMA2(((v2f)(wv1)),  pfx##a1,  res); \
  res = FMA2(((v2f)(wv2)),  pfx##a2,  res); \
  res = FMA2(((v2f)(wv3)),  pfx##a3,  res); \
  res = FMA2(((v2f)(wv4)),  pfx##a4,  res); \
  res = FMA2(((v2f)(wv5)),  pfx##a5,  res); \
  res = FMA2(((v2f)(wv6)),  pfx##a6,  res); \
  res = FMA2(((v2f)(wv7)),  pfx##a7,  res); \
  res = FMA2(((v2f)(wv8)),  pfx##a8,  res); \
  res = FMA2(((v2f)(wv9)),  pfx##a9,  res); \
  res = FMA2(((v2f)(wv10)), pfx##a10, res);

// phase q: DMA row R0+8+q (3 phases ahead) into freed slot, counted vmcnt(6)
// (rows q+11,q+12,q+13 = 6 instrs stay in flight -> row q+10's slot landed),
// h-blur new slot, vertical blur over named ring slots, SSIM epilogue.
#define PHASE(QV, SNEW, SDMA, a0,a1,a2,a3,a4,a5,a6,a7,a8,a9,a10) { \
  const int rw_ = R0 + 8 + (QV); \
  dma_row(&lds[SDMA][0], rowaddr(pX, rw_, colOK, zp), rowaddr(pY, rw_, colOK, zp), t); \
  asm volatile("s_waitcnt vmcnt(6)" ::: "memory"); \
  HBLUR(SNEW) \
  { v2f mx, my, ex2, ey2, exy; \
    VSUM(mx,  hx,   a0,a1,a2,a3,a4,a5,a6,a7,a8,a9,a10) \
    VSUM(my,  hy,   a0,a1,a2,a3,a4,a5,a6,a7,a8,a9,a10) \
    VSUM(ex2, hx2_, a0,a1,a2,a3,a4,a5,a6,a7,a8,a9,a10) \
    VSUM(ey2, hy2_, a0,a1,a2,a3,a4,a5,a6,a7,a8,a9,a10) \
    VSUM(exy, hxy,  a0,a1,a2,a3,a4,a5,a6,a7,a8,a9,a10) \
    const v2f mx2 = mx*mx, my2 = my*my, mxy = mx*my; \
    const v2f sx2v = ex2 - mx2, sy2v = ey2 - my2, sxyv = exy - mxy; \
    const v2f num = (2.f*mxy + C1V) * (2.f*sxyv + C2V); \
    const v2f den = (mx2 + my2 + C1V) * (sx2v + sy2v + C2V) + EPSV; \
    v2f rc_; rc_.x = __builtin_amdgcn_rcpf(den.x); rc_.y = __builtin_amdgcn_rcpf(den.y); \
    acc = FMA2(num, rc_, acc); } }

__global__ __launch_bounds__(BLOCK)
__attribute__((amdgpu_waves_per_eu(2)))
void ssim_main(const float* __restrict__ x, const float* __restrict__ y,
               float* __restrict__ ws)
{
  __shared__ float lds[NS][SLOT_F];   // 12.7 KB

  const int t = threadIdx.x;
  const int colT = blockIdx.x & (COL_TILES - 1);
  const int rowT = blockIdx.x >> 2;
  const int plane = blockIdx.y;
  const int C0 = colT * COLS_PB;
  const int R0 = rowT * ROWS_PB;

  const float* xp = x + (ptrdiff_t)plane * (HH * WW);
  const float* yp = y + (ptrdiff_t)plane * (HH * WW);
  const float* zp = ws;               // 256-float zero page (zeroed each launch)
  float* partial = ws + 256;

  // Gaussian window (exact reference formula), named scalars -> SGPRs.
  float wv0, wv1, wv2, wv3, wv4, wv5, wv6, wv7, wv8, wv9, wv10;
#define WINIT(k) wv##k = expf(-((float)((k - 5) * (k - 5))) / 4.5f);
  WINIT(0) WINIT(1) WINIT(2) WINIT(3) WINIT(4) WINIT(5)
  WINIT(6) WINIT(7) WINIT(8) WINIT(9) WINIT(10)
#undef WINIT
  const float inv_ = 1.f / (wv0 + wv1 + wv2 + wv3 + wv4 + wv5 + wv6 + wv7 + wv8 + wv9 + wv10);
#define WNORM(k) wv##k = __int_as_float(__builtin_amdgcn_readfirstlane(__float_as_int(wv##k * inv_)));
  WNORM(0) WNORM(1) WNORM(2) WNORM(3) WNORM(4) WNORM(5)
  WNORM(6) WNORM(7) WNORM(8) WNORM(9) WNORM(10)
#undef WNORM

  // per-lane DMA source descriptors (named scalars only)
  const int gc = C0 - PADL + 4 * t;
  const bool colOK = (gc >= 0) && (gc + 3 < WW);
  const float* pX = xp + gc;
  const float* pY = yp + gc;

  // named ring: 11 slots x 5 quantities x v2f (110 VGPRs, zero aggregates)
  v2f hx0,hx1,hx2,hx3,hx4,hx5,hx6,hx7,hx8,hx9,hx10;
  v2f hy0,hy1,hy2,hy3,hy4,hy5,hy6,hy7,hy8,hy9,hy10;
  v2f hx2_0,hx2_1,hx2_2,hx2_3,hx2_4,hx2_5,hx2_6,hx2_7,hx2_8,hx2_9,hx2_10;
  v2f hy2_0,hy2_1,hy2_2,hy2_3,hy2_4,hy2_5,hy2_6,hy2_7,hy2_8,hy2_9,hy2_10;
  v2f hxy0,hxy1,hxy2,hxy3,hxy4,hxy5,hxy6,hxy7,hxy8,hxy9,hxy10;
  v2f acc = {0.f, 0.f};

  // prologue: DMA rows R0-5..R0+5 -> slots 0..10, then rows R0+6,R0+7 -> slots 0,1
  for (int s = 0; s < NS; ++s)
    dma_row(&lds[s][0], rowaddr(pX, R0 - HALO + s, colOK, zp),
            rowaddr(pY, R0 - HALO + s, colOK, zp), t);
  dma_row(&lds[0][0], rowaddr(pX, R0 + 6, colOK, zp), rowaddr(pY, R0 + 6, colOK, zp), t);
  dma_row(&lds[1][0], rowaddr(pX, R0 + 7, colOK, zp), rowaddr(pY, R0 + 7, colOK, zp), t);
  asm volatile("s_waitcnt vmcnt(6)" ::: "memory");   // slots 0..9 landed

  // ring fill: h-blur raw rows R0-5..R0+4 (slots 0..9)
  HBLUR(0) HBLUR(1) HBLUR(2) HBLUR(3) HBLUR(4)
  HBLUR(5) HBLUR(6) HBLUR(7) HBLUR(8) HBLUR(9)

  // 64 live phases: 5 groups x 11 + 9 tail (q = 55..63), uniform vmcnt schedule
  #pragma unroll 1
  for (int g = 0; g < 5; ++g) {
    const int qb = 11 * g;
    PHASE(qb + 0 , 10, 2,  0,1,2,3,4,5,6,7,8,9,10)
    PHASE(qb + 1 , 0 , 3,  1,2,3,4,5,6,7,8,9,10,0)
    PHASE(qb + 2 , 1 , 4,  2,3,4,5,6,7,8,9,10,0,1)
    PHASE(qb + 3 , 2 , 5,  3,4,5,6,7,8,9,10,0,1,2)
    PHASE(qb + 4 , 3 , 6,  4,5,6,7,8,9,10,0,1,2,3)
    PHASE(qb + 5 , 4 , 7,  5,6,7,8,9,10,0,1,2,3,4)
    PHASE(qb + 6 , 5 , 8,  6,7,8,9,10,0,1,2,3,4,5)
    PHASE(qb + 7 , 6 , 9,  7,8,9,10,0,1,2,3,4,5,6)
    PHASE(qb + 8 , 7 , 10, 8,9,10,0,1,2,3,4,5,6,7)
    PHASE(qb + 9 , 8 , 0,  9,10,0,1,2,3,4,5,6,7,8)
    PHASE(qb + 10, 9 , 1,  10,0,1,2,3,4,5,6,7,8,9)
  }
  PHASE(55, 10, 2,  0,1,2,3,4,5,6,7,8,9,10)
  PHASE(56, 0 , 3,  1,2,3,4,5,6,7,8,9,10,0)
  PHASE(57, 1 , 4,  2,3,4,5,6,7,8,9,10,0,1)
  PHASE(58, 2 , 5,  3,4,5,6,7,8,9,10,0,1,2)
  PHASE(59, 3 , 6,  4,5,6,7,8,9,10,0,1,2,3)
  PHASE(60, 4 , 7,  5,6,7,8,9,10,0,1,2,3,4)
  PHASE(61, 5 , 8,  6,7,8,9,10,0,1,2,3,4,5)
  PHASE(62, 6 , 9,  7,8,9,10,0,1,2,3,4,5,6)
  PHASE(63, 7 , 10, 8,9,10,0,1,2,3,4,5,6,7)

  // drain outstanding DMA before LDS goes away
  asm volatile("s_waitcnt vmcnt(0)" ::: "memory");

  // single-wave shuffle reduction -> deterministic per-block partial
  float a = acc.x + acc.y;
  #pragma unroll
  for (int off = 32; off > 0; off >>= 1) a += __shfl_down(a, off);
  if (t == 0) partial[blockIdx.y * (COL_TILES * ROW_TILES) + blockIdx.x] = a;
}

__global__ void zero_ws_kernel(float* __restrict__ ws)
{
  ws[threadIdx.x] = 0.f;   // zero page
}

__global__ void finalize_kernel(const float* __restrict__ partial, float* __restrict__ out)
{
  __shared__ float s4[4];
  float a = 0.f;
  for (int i = threadIdx.x; i < NBLK; i += 256) a += partial[i];
  #pragma unroll
  for (int off = 32; off > 0; off >>= 1) a += __shfl_down(a, off);
  if ((threadIdx.x & 63) == 0) s4[threadIdx.x >> 6] = a;
  __syncthreads();
  if (threadIdx.x == 0) out[0] = 1.f - (s4[0] + s4[1] + s4[2] + s4[3]) * (1.f / NPIX);
}

extern "C" void kernel_launch(void* const* d_in, const int* in_sizes, int n_in,
                              void* d_out, int out_size, void* d_ws, size_t ws_size,
                              hipStream_t stream)
{
  const float* x = (const float*)d_in[0];
  const float* y = (const float*)d_in[1];
  float* ws = (float*)d_ws;
  float* out = (float*)d_out;

  hipLaunchKernelGGL(zero_ws_kernel, dim3(1), dim3(256), 0, stream, ws);
  hipLaunchKernelGGL(ssim_main, dim3(COL_TILES * ROW_TILES, NPLANES), dim3(BLOCK),
                     0, stream, x, y, ws);
  hipLaunchKernelGGL(finalize_kernel, dim3(1), dim3(256), 0, stream, ws + 256, out);
}

// Round 7
// 124.592 us; speedup vs baseline: 5.9103x; 3.9437x over previous
//
#include <hip/hip_runtime.h>

typedef float v2f __attribute__((ext_vector_type(2)));

#define HH 512
#define WW 512
#define NPLANES 96
#define BLOCK 64          // 1 wave per block -> no barriers anywhere
#define COLS_PB 64        // 1 column per thread
#define ROWS_PB 128
#define COL_TILES 8       // 512 / 64
#define ROW_TILES 4       // 512 / 128
#define HALO 5
#define NS 11             // LDS raw-row ring slots == named register ring depth
#define SLOT_F 256        // x floats [0,80), y [80,160), junk tail [160,256)
#define PADL 8            // LDS x float i <-> global col C0-8+i
#define NOUT 128

#define C1V 1e-4f
#define C2V 9e-4f
#define EPSV 1e-8f
#define NPIX 25165824.0f  // 32*3*512*512
#define NBLK (COL_TILES * ROW_TILES * NPLANES)   // 3072

#define FMA2(a,b,c) __builtin_elementwise_fma((a),(b),(c))

__device__ __forceinline__ void gld16(const float* g, float* l) {
  __builtin_amdgcn_global_load_lds((const __attribute__((address_space(1))) void*)g,
                                   (__attribute__((address_space(3))) void*)l, 16, 0, 0);
}

// ---- all ring/weight/tap values are NAMED variables (no arrays anywhere) ----

// one 11-tap horizontal blur, {x,y} packed per v2f lane-pair:
//   a = {sum w*x, sum w*y}, b = {sum w*x^2, sum w*y^2}, c = sum w*x*y
#define TAP(K) { \
  const v2f tk = { ldsF[bb_ + K], ldsF[bb_ + 80 + K] }; \
  const v2f wt = wv##K * tk; \
  sa += wt; sb = FMA2(wt, tk, sb); sc = fmaf(wt.x, tk.y, sc); }

#define HBLUR(S) { \
  const int bb_ = (S) * SLOT_F + t + 3; \
  v2f sa = {0.f, 0.f}, sb = {0.f, 0.f}; float sc = 0.f; \
  TAP(0) TAP(1) TAP(2) TAP(3) TAP(4) TAP(5) \
  TAP(6) TAP(7) TAP(8) TAP(9) TAP(10) \
  a##S = sa; b##S = sb; c##S = sc; }

// vertical 11-tap blur over named ring slots + SSIM epilogue
#define VEPI(p0,p1,p2,p3,p4,p5,p6,p7,p8,p9,p10) { \
  v2f ma = wv0 * a##p0; \
  ma = FMA2((v2f)(wv1),  a##p1,  ma); ma = FMA2((v2f)(wv2),  a##p2,  ma); \
  ma = FMA2((v2f)(wv3),  a##p3,  ma); ma = FMA2((v2f)(wv4),  a##p4,  ma); \
  ma = FMA2((v2f)(wv5),  a##p5,  ma); ma = FMA2((v2f)(wv6),  a##p6,  ma); \
  ma = FMA2((v2f)(wv7),  a##p7,  ma); ma = FMA2((v2f)(wv8),  a##p8,  ma); \
  ma = FMA2((v2f)(wv9),  a##p9,  ma); ma = FMA2((v2f)(wv10), a##p10, ma); \
  v2f mb = wv0 * b##p0; \
  mb = FMA2((v2f)(wv1),  b##p1,  mb); mb = FMA2((v2f)(wv2),  b##p2,  mb); \
  mb = FMA2((v2f)(wv3),  b##p3,  mb); mb = FMA2((v2f)(wv4),  b##p4,  mb); \
  mb = FMA2((v2f)(wv5),  b##p5,  mb); mb = FMA2((v2f)(wv6),  b##p6,  mb); \
  mb = FMA2((v2f)(wv7),  b##p7,  mb); mb = FMA2((v2f)(wv8),  b##p8,  mb); \
  mb = FMA2((v2f)(wv9),  b##p9,  mb); mb = FMA2((v2f)(wv10), b##p10, mb); \
  float mc = wv0 * c##p0; \
  mc = fmaf(wv1,  c##p1,  mc); mc = fmaf(wv2,  c##p2,  mc); \
  mc = fmaf(wv3,  c##p3,  mc); mc = fmaf(wv4,  c##p4,  mc); \
  mc = fmaf(wv5,  c##p5,  mc); mc = fmaf(wv6,  c##p6,  mc); \
  mc = fmaf(wv7,  c##p7,  mc); mc = fmaf(wv8,  c##p8,  mc); \
  mc = fmaf(wv9,  c##p9,  mc); mc = fmaf(wv10, c##p10, mc); \
  const v2f mm = ma * ma;                 /* {mx2, my2} */ \
  const float mxy = ma.x * ma.y; \
  const v2f sv = mb - mm;                 /* {sx2, sy2} */ \
  const float sxy = mc - mxy; \
  const float num = fmaf(2.f, mxy, C1V) * fmaf(2.f, sxy, C2V); \
  const float den = (mm.x + mm.y + C1V) * (sv.x + sv.y + C2V) + EPSV; \
  acc = fmaf(num, __builtin_amdgcn_rcpf(den), acc); }

// phase q: DMA row R0+8+q (1 instr; 3 rows in flight) into retired slot
// (q+2)%11, counted vmcnt(3) -> row R0+5+q landed, h-blur it into ring slot
// (q+10)%11, vertical blur + epilogue for output row R0+q.
#define PHASE(QV, SNEW, SDMA, p0,p1,p2,p3,p4,p5,p6,p7,p8,p9,p10) { \
  const int rw_ = R0 + 8 + (QV); \
  const float* sa_ = ((unsigned)rw_ < (unsigned)HH) \
      ? (const float*)((uintptr_t)pSrc + (unsigned)rw_ * strB) : zp; \
  gld16(sa_, ldsF + (SDMA) * SLOT_F); \
  asm volatile("s_waitcnt vmcnt(3)" ::: "memory"); \
  HBLUR(SNEW) \
  VEPI(p0,p1,p2,p3,p4,p5,p6,p7,p8,p9,p10) }

__global__ __launch_bounds__(BLOCK)
void ssim_main(const float* __restrict__ x, const float* __restrict__ y,
               float* __restrict__ ws)
{
  __shared__ float ldsF[NS * SLOT_F];   // 11 KB

  const int t = threadIdx.x;
  const int colT = blockIdx.x & (COL_TILES - 1);
  const int rowT = blockIdx.x >> 3;
  const int plane = blockIdx.y;
  const int C0 = colT * COLS_PB;
  const int R0 = rowT * ROWS_PB;

  const float* xp = x + (ptrdiff_t)plane * (HH * WW);
  const float* yp = y + (ptrdiff_t)plane * (HH * WW);
  const float* zp = ws;                 // 256-float zero page (zeroed each launch)
  float* partial = ws + 256;

  // Gaussian window (exact reference formula), named scalars -> SGPRs
  float wv0, wv1, wv2, wv3, wv4, wv5, wv6, wv7, wv8, wv9, wv10;
#define WINIT(k) wv##k = expf(-((float)((k - 5) * (k - 5))) / 4.5f);
  WINIT(0) WINIT(1) WINIT(2) WINIT(3) WINIT(4) WINIT(5)
  WINIT(6) WINIT(7) WINIT(8) WINIT(9) WINIT(10)
#undef WINIT
  const float inv_ = 1.f / (wv0 + wv1 + wv2 + wv3 + wv4 + wv5 + wv6 + wv7 + wv8 + wv9 + wv10);
#define WNORM(k) wv##k = __int_as_float(__builtin_amdgcn_readfirstlane(__float_as_int(wv##k * inv_)));
  WNORM(0) WNORM(1) WNORM(2) WNORM(3) WNORM(4) WNORM(5)
  WNORM(6) WNORM(7) WNORM(8) WNORM(9) WNORM(10)
#undef WNORM

  // per-lane DMA source: lanes 0..19 -> x chunks, 20..39 -> y chunks, rest zp.
  // LDS dest is wave-uniform base + lane*16 (HW rule) -> x lands [0,320)B,
  // y [320,640)B, junk [640,1024)B of each 1 KB slot.
  const int  lsub  = (t < 20) ? t : (t - 20);
  const int  gcol  = C0 - PADL + 4 * lsub;
  const bool colOK = (t < 40) && (gcol >= 0) && (gcol + 3 < WW);
  const float* pSrc = colOK ? (((t < 20) ? xp : yp) + gcol) : zp;
  const unsigned strB = colOK ? (unsigned)(WW * 4) : 0u;

  // named ring: 11 slots x {a:v2f, b:v2f, c:float} = 55 VGPRs
  v2f a0,a1,a2,a3,a4,a5,a6,a7,a8,a9,a10;
  v2f b0,b1,b2,b3,b4,b5,b6,b7,b8,b9,b10;
  float c0,c1,c2,c3,c4,c5,c6,c7,c8,c9,c10;
  float acc = 0.f;

  // prologue: rows R0-5..R0+5 -> slots 0..10, rows R0+6,R0+7 -> slots 0,1
  for (int s = 0; s < NS; ++s) {
    const int rw = R0 - HALO + s;
    const float* sa_ = ((unsigned)rw < (unsigned)HH)
        ? (const float*)((uintptr_t)pSrc + (unsigned)rw * strB) : zp;
    gld16(sa_, ldsF + s * SLOT_F);
  }
  {
    const int rw = R0 + 6;
    const float* sa_ = ((unsigned)rw < (unsigned)HH)
        ? (const float*)((uintptr_t)pSrc + (unsigned)rw * strB) : zp;
    gld16(sa_, ldsF + 0 * SLOT_F);
  }
  {
    const int rw = R0 + 7;
    const float* sa_ = ((unsigned)rw < (unsigned)HH)
        ? (const float*)((uintptr_t)pSrc + (unsigned)rw * strB) : zp;
    gld16(sa_, ldsF + 1 * SLOT_F);
  }
  asm volatile("s_waitcnt vmcnt(3)" ::: "memory");   // slots 0..9 landed

  // ring fill: h-blur raw rows R0-5..R0+4 (slots 0..9)
  HBLUR(0) HBLUR(1) HBLUR(2) HBLUR(3) HBLUR(4)
  HBLUR(5) HBLUR(6) HBLUR(7) HBLUR(8) HBLUR(9)

  // 128 live phases: 11 groups x 11 + 7 tail, uniform vmcnt schedule
  #pragma unroll 1
  for (int g = 0; g < 11; ++g) {
    const int qb = 11 * g;
    PHASE(qb + 0 , 10, 2,  0,1,2,3,4,5,6,7,8,9,10)
    PHASE(qb + 1 , 0 , 3,  1,2,3,4,5,6,7,8,9,10,0)
    PHASE(qb + 2 , 1 , 4,  2,3,4,5,6,7,8,9,10,0,1)
    PHASE(qb + 3 , 2 , 5,  3,4,5,6,7,8,9,10,0,1,2)
    PHASE(qb + 4 , 3 , 6,  4,5,6,7,8,9,10,0,1,2,3)
    PHASE(qb + 5 , 4 , 7,  5,6,7,8,9,10,0,1,2,3,4)
    PHASE(qb + 6 , 5 , 8,  6,7,8,9,10,0,1,2,3,4,5)
    PHASE(qb + 7 , 6 , 9,  7,8,9,10,0,1,2,3,4,5,6)
    PHASE(qb + 8 , 7 , 10, 8,9,10,0,1,2,3,4,5,6,7)
    PHASE(qb + 9 , 8 , 0,  9,10,0,1,2,3,4,5,6,7,8)
    PHASE(qb + 10, 9 , 1,  10,0,1,2,3,4,5,6,7,8,9)
  }
  PHASE(121, 10, 2,  0,1,2,3,4,5,6,7,8,9,10)
  PHASE(122, 0 , 3,  1,2,3,4,5,6,7,8,9,10,0)
  PHASE(123, 1 , 4,  2,3,4,5,6,7,8,9,10,0,1)
  PHASE(124, 2 , 5,  3,4,5,6,7,8,9,10,0,1,2)
  PHASE(125, 3 , 6,  4,5,6,7,8,9,10,0,1,2,3)
  PHASE(126, 4 , 7,  5,6,7,8,9,10,0,1,2,3,4)
  PHASE(127, 5 , 8,  6,7,8,9,10,0,1,2,3,4,5)

  // drain outstanding DMA before LDS goes away
  asm volatile("s_waitcnt vmcnt(0)" ::: "memory");

  // single-wave shuffle reduction -> deterministic per-block partial
  float a = acc;
  #pragma unroll
  for (int off = 32; off > 0; off >>= 1) a += __shfl_down(a, off);
  if (t == 0) partial[blockIdx.y * (COL_TILES * ROW_TILES) + blockIdx.x] = a;
}

__global__ void zero_ws_kernel(float* __restrict__ ws)
{
  ws[threadIdx.x] = 0.f;   // zero page
}

__global__ void finalize_kernel(const float* __restrict__ partial, float* __restrict__ out)
{
  __shared__ float s4[4];
  float a = 0.f;
  for (int i = threadIdx.x; i < NBLK; i += 256) a += partial[i];
  #pragma unroll
  for (int off = 32; off > 0; off >>= 1) a += __shfl_down(a, off);
  if ((threadIdx.x & 63) == 0) s4[threadIdx.x >> 6] = a;
  __syncthreads();
  if (threadIdx.x == 0) out[0] = 1.f - (s4[0] + s4[1] + s4[2] + s4[3]) * (1.f / NPIX);
}

extern "C" void kernel_launch(void* const* d_in, const int* in_sizes, int n_in,
                              void* d_out, int out_size, void* d_ws, size_t ws_size,
                              hipStream_t stream)
{
  const float* x = (const float*)d_in[0];
  const float* y = (const float*)d_in[1];
  float* ws = (float*)d_ws;
  float* out = (float*)d_out;

  hipLaunchKernelGGL(zero_ws_kernel, dim3(1), dim3(256), 0, stream, ws);
  hipLaunchKernelGGL(ssim_main, dim3(COL_TILES * ROW_TILES, NPLANES), dim3(BLOCK),
                     0, stream, x, y, ws);
  hipLaunchKernelGGL(finalize_kernel, dim3(1), dim3(256), 0, stream, ws + 256, out);
}

// Round 8
// 121.652 us; speedup vs baseline: 6.0532x; 1.0242x over previous
//
#include <hip/hip_runtime.h>

typedef float v2f __attribute__((ext_vector_type(2)));

#define HH 512
#define WW 512
#define NPLANES 96
#define BLOCK 64          // 1 wave per block -> no barriers anywhere
#define COLS_PB 64        // 1 column per thread
#define ROWS_PB 64
#define COL_TILES 8       // 512 / 64
#define ROW_TILES 8       // 512 / 64
#define HALO 5
#define NS 11             // LDS ring slots == named register ring depth
#define SLOT_V2 96        // v2f pairs per slot (192 floats; data pairs 0..79, junk 80..95)
#define PADL 8            // pair p <-> global col C0-8+p
#define NOUT 64

#define C1V 1e-4f
#define C2V 9e-4f
#define EPSV 1e-8f
#define NPIX 25165824.0f  // 32*3*512*512
#define NBLK (COL_TILES * ROW_TILES * NPLANES)   // 6144

#define FMA2(a,b,c) __builtin_elementwise_fma((a),(b),(c))

__device__ __forceinline__ void gld4(const float* g, float* l) {
  __builtin_amdgcn_global_load_lds((const __attribute__((address_space(1))) void*)g,
                                   (__attribute__((address_space(3))) void*)l, 4, 0, 0);
}

// stage one interleaved {x,y} row into a slot: 3 DMA instrs (4B/lane), rows
// out of [0,512) read the zero page (stride 0 folds col-invalid lanes too).
__device__ __forceinline__ void dma_rowpair(float* dst, int rw,
    const float* pS0, unsigned st0, const float* pS1, unsigned st1,
    const float* pS2, unsigned st2, const float* zp)
{
  const bool rok = (unsigned)rw < (unsigned)HH;
  const float* a0 = rok ? (const float*)((uintptr_t)pS0 + (unsigned)rw * st0) : zp;
  const float* a1 = rok ? (const float*)((uintptr_t)pS1 + (unsigned)rw * st1) : zp;
  const float* a2 = rok ? (const float*)((uintptr_t)pS2 + (unsigned)rw * st2) : zp;
  gld4(a0, dst);
  gld4(a1, dst + 64);
  gld4(a2, dst + 128);
}

// ---- named variables only (no arrays -> nothing can fall to scratch) ----

// tap k of thread t: one aligned ds_read_b64 gives {x,y} directly
#define TAP(K) { \
  const v2f tk = pb_[K]; \
  const v2f wt = wv##K * tk; \
  sa += wt; sb = FMA2(wt, tk, sb); sc = fmaf(wt.x, tk.y, sc); }

#define HBLUR(S) { \
  const v2f* pb_ = ldsv2 + (S) * SLOT_V2 + t + 3; \
  v2f sa = {0.f, 0.f}, sb = {0.f, 0.f}; float sc = 0.f; \
  TAP(0) TAP(1) TAP(2) TAP(3) TAP(4) TAP(5) \
  TAP(6) TAP(7) TAP(8) TAP(9) TAP(10) \
  a##S = sa; b##S = sb; c##S = sc; }

// vertical 11-tap blur over named ring slots + SSIM epilogue
#define VEPI(p0,p1,p2,p3,p4,p5,p6,p7,p8,p9,p10) { \
  v2f ma = wv0 * a##p0; \
  ma = FMA2((v2f)(wv1),  a##p1,  ma); ma = FMA2((v2f)(wv2),  a##p2,  ma); \
  ma = FMA2((v2f)(wv3),  a##p3,  ma); ma = FMA2((v2f)(wv4),  a##p4,  ma); \
  ma = FMA2((v2f)(wv5),  a##p5,  ma); ma = FMA2((v2f)(wv6),  a##p6,  ma); \
  ma = FMA2((v2f)(wv7),  a##p7,  ma); ma = FMA2((v2f)(wv8),  a##p8,  ma); \
  ma = FMA2((v2f)(wv9),  a##p9,  ma); ma = FMA2((v2f)(wv10), a##p10, ma); \
  v2f mb = wv0 * b##p0; \
  mb = FMA2((v2f)(wv1),  b##p1,  mb); mb = FMA2((v2f)(wv2),  b##p2,  mb); \
  mb = FMA2((v2f)(wv3),  b##p3,  mb); mb = FMA2((v2f)(wv4),  b##p4,  mb); \
  mb = FMA2((v2f)(wv5),  b##p5,  mb); mb = FMA2((v2f)(wv6),  b##p6,  mb); \
  mb = FMA2((v2f)(wv7),  b##p7,  mb); mb = FMA2((v2f)(wv8),  b##p8,  mb); \
  mb = FMA2((v2f)(wv9),  b##p9,  mb); mb = FMA2((v2f)(wv10), b##p10, mb); \
  float mc = wv0 * c##p0; \
  mc = fmaf(wv1,  c##p1,  mc); mc = fmaf(wv2,  c##p2,  mc); \
  mc = fmaf(wv3,  c##p3,  mc); mc = fmaf(wv4,  c##p4,  mc); \
  mc = fmaf(wv5,  c##p5,  mc); mc = fmaf(wv6,  c##p6,  mc); \
  mc = fmaf(wv7,  c##p7,  mc); mc = fmaf(wv8,  c##p8,  mc); \
  mc = fmaf(wv9,  c##p9,  mc); mc = fmaf(wv10, c##p10, mc); \
  const v2f mm = ma * ma;                 /* {mx2, my2} */ \
  const float mxy = ma.x * ma.y; \
  const v2f sv = mb - mm;                 /* {sx2, sy2} */ \
  const float sxy = mc - mxy; \
  const float num = fmaf(2.f, mxy, C1V) * fmaf(2.f, sxy, C2V); \
  const float den = (mm.x + mm.y + C1V) * (sv.x + sv.y + C2V) + EPSV; \
  acc = fmaf(num, __builtin_amdgcn_rcpf(den), acc); }

// phase q: DMA row R0+8+q (3 instrs; 3 rows = 9 instrs in flight) into retired
// slot (q+2)%11, counted vmcnt(9) -> row R0+5+q landed, h-blur it into ring
// slot (q+10)%11, vertical blur + epilogue for output row R0+q.
#define PHASE(QV, SNEW, SDMA, p0,p1,p2,p3,p4,p5,p6,p7,p8,p9,p10) { \
  dma_rowpair(ldsF + (SDMA) * (SLOT_V2 * 2), R0 + 8 + (QV), \
              pS0, st0, pS1, st1, pS2, st2, zp); \
  asm volatile("s_waitcnt vmcnt(9)" ::: "memory"); \
  HBLUR(SNEW) \
  VEPI(p0,p1,p2,p3,p4,p5,p6,p7,p8,p9,p10) }

__global__ __launch_bounds__(BLOCK)
void ssim_main(const float* __restrict__ x, const float* __restrict__ y,
               float* __restrict__ ws)
{
  __shared__ float ldsF[NS * SLOT_V2 * 2];   // 8.25 KB

  const int t = threadIdx.x;
  const int colT = blockIdx.x & (COL_TILES - 1);
  const int rowT = blockIdx.x >> 3;
  const int plane = blockIdx.y;
  const int C0 = colT * COLS_PB;
  const int R0 = rowT * ROWS_PB;

  const float* xp = x + (ptrdiff_t)plane * (HH * WW);
  const float* yp = y + (ptrdiff_t)plane * (HH * WW);
  const float* zp = ws;                 // 256-float zero page (zeroed each launch)
  float* partial = ws + 256;
  const v2f* ldsv2 = (const v2f*)ldsF;

  // Gaussian window (exact reference formula), named scalars -> SGPRs
  float wv0, wv1, wv2, wv3, wv4, wv5, wv6, wv7, wv8, wv9, wv10;
#define WINIT(k) wv##k = expf(-((float)((k - 5) * (k - 5))) / 4.5f);
  WINIT(0) WINIT(1) WINIT(2) WINIT(3) WINIT(4) WINIT(5)
  WINIT(6) WINIT(7) WINIT(8) WINIT(9) WINIT(10)
#undef WINIT
  const float inv_ = 1.f / (wv0 + wv1 + wv2 + wv3 + wv4 + wv5 + wv6 + wv7 + wv8 + wv9 + wv10);
#define WNORM(k) wv##k = __int_as_float(__builtin_amdgcn_readfirstlane(__float_as_int(wv##k * inv_)));
  WNORM(0) WNORM(1) WNORM(2) WNORM(3) WNORM(4) WNORM(5)
  WNORM(6) WNORM(7) WNORM(8) WNORM(9) WNORM(10)
#undef WNORM

  // per-lane DMA sources: slot float f = 64*i + lane; pair p=f>>1 (col C0-8+p),
  // even floats source x, odd source y. Invalid lanes read zero page (stride 0).
  const float *pS0, *pS1, *pS2;
  unsigned st0, st1, st2;
#define MKSRC(i, PS, ST) { \
  const int fidx = 64 * (i) + t; \
  const int p = fidx >> 1; \
  const int gcol = C0 - PADL + p; \
  const bool ok = (p < 80) && (gcol >= 0) && (gcol < WW); \
  PS = ok ? (((fidx & 1) ? yp : xp) + gcol) : zp; \
  ST = ok ? (unsigned)(WW * 4) : 0u; }
  MKSRC(0, pS0, st0)
  MKSRC(1, pS1, st1)
  MKSRC(2, pS2, st2)
#undef MKSRC

  // named ring: 11 slots x {a:v2f, b:v2f, c:float} = 55 VGPRs
  v2f a0,a1,a2,a3,a4,a5,a6,a7,a8,a9,a10;
  v2f b0,b1,b2,b3,b4,b5,b6,b7,b8,b9,b10;
  float c0,c1,c2,c3,c4,c5,c6,c7,c8,c9,c10;
  float acc = 0.f;

  // prologue: rows R0-5..R0+5 -> slots 0..10, rows R0+6,R0+7 -> slots 0,1
  for (int s = 0; s < NS; ++s)
    dma_rowpair(ldsF + s * (SLOT_V2 * 2), R0 - HALO + s, pS0, st0, pS1, st1, pS2, st2, zp);
  dma_rowpair(ldsF + 0 * (SLOT_V2 * 2), R0 + 6, pS0, st0, pS1, st1, pS2, st2, zp);
  dma_rowpair(ldsF + 1 * (SLOT_V2 * 2), R0 + 7, pS0, st0, pS1, st1, pS2, st2, zp);
  asm volatile("s_waitcnt vmcnt(9)" ::: "memory");   // slots 0..9 landed

  // ring fill: h-blur raw rows R0-5..R0+4 (slots 0..9)
  HBLUR(0) HBLUR(1) HBLUR(2) HBLUR(3) HBLUR(4)
  HBLUR(5) HBLUR(6) HBLUR(7) HBLUR(8) HBLUR(9)

  // 64 live phases: 5 groups x 11 + 9 tail, uniform vmcnt schedule
  #pragma unroll 1
  for (int g = 0; g < 5; ++g) {
    const int qb = 11 * g;
    PHASE(qb + 0 , 10, 2,  0,1,2,3,4,5,6,7,8,9,10)
    PHASE(qb + 1 , 0 , 3,  1,2,3,4,5,6,7,8,9,10,0)
    PHASE(qb + 2 , 1 , 4,  2,3,4,5,6,7,8,9,10,0,1)
    PHASE(qb + 3 , 2 , 5,  3,4,5,6,7,8,9,10,0,1,2)
    PHASE(qb + 4 , 3 , 6,  4,5,6,7,8,9,10,0,1,2,3)
    PHASE(qb + 5 , 4 , 7,  5,6,7,8,9,10,0,1,2,3,4)
    PHASE(qb + 6 , 5 , 8,  6,7,8,9,10,0,1,2,3,4,5)
    PHASE(qb + 7 , 6 , 9,  7,8,9,10,0,1,2,3,4,5,6)
    PHASE(qb + 8 , 7 , 10, 8,9,10,0,1,2,3,4,5,6,7)
    PHASE(qb + 9 , 8 , 0,  9,10,0,1,2,3,4,5,6,7,8)
    PHASE(qb + 10, 9 , 1,  10,0,1,2,3,4,5,6,7,8,9)
  }
  PHASE(55, 10, 2,  0,1,2,3,4,5,6,7,8,9,10)
  PHASE(56, 0 , 3,  1,2,3,4,5,6,7,8,9,10,0)
  PHASE(57, 1 , 4,  2,3,4,5,6,7,8,9,10,0,1)
  PHASE(58, 2 , 5,  3,4,5,6,7,8,9,10,0,1,2)
  PHASE(59, 3 , 6,  4,5,6,7,8,9,10,0,1,2,3)
  PHASE(60, 4 , 7,  5,6,7,8,9,10,0,1,2,3,4)
  PHASE(61, 5 , 8,  6,7,8,9,10,0,1,2,3,4,5)
  PHASE(62, 6 , 9,  7,8,9,10,0,1,2,3,4,5,6)
  PHASE(63, 7 , 10, 8,9,10,0,1,2,3,4,5,6,7)

  // drain outstanding DMA before LDS goes away
  asm volatile("s_waitcnt vmcnt(0)" ::: "memory");

  // single-wave shuffle reduction -> deterministic per-block partial
  float a = acc;
  #pragma unroll
  for (int off = 32; off > 0; off >>= 1) a += __shfl_down(a, off);
  if (t == 0) partial[blockIdx.y * (COL_TILES * ROW_TILES) + blockIdx.x] = a;
}

__global__ void zero_ws_kernel(float* __restrict__ ws)
{
  ws[threadIdx.x] = 0.f;   // zero page
}

__global__ void finalize_kernel(const float* __restrict__ partial, float* __restrict__ out)
{
  __shared__ float s4[4];
  float a = 0.f;
  for (int i = threadIdx.x; i < NBLK; i += 256) a += partial[i];
  #pragma unroll
  for (int off = 32; off > 0; off >>= 1) a += __shfl_down(a, off);
  if ((threadIdx.x & 63) == 0) s4[threadIdx.x >> 6] = a;
  __syncthreads();
  if (threadIdx.x == 0) out[0] = 1.f - (s4[0] + s4[1] + s4[2] + s4[3]) * (1.f / NPIX);
}

extern "C" void kernel_launch(void* const* d_in, const int* in_sizes, int n_in,
                              void* d_out, int out_size, void* d_ws, size_t ws_size,
                              hipStream_t stream)
{
  const float* x = (const float*)d_in[0];
  const float* y = (const float*)d_in[1];
  float* ws = (float*)d_ws;
  float* out = (float*)d_out;

  hipLaunchKernelGGL(zero_ws_kernel, dim3(1), dim3(256), 0, stream, ws);
  hipLaunchKernelGGL(ssim_main, dim3(COL_TILES * ROW_TILES, NPLANES), dim3(BLOCK),
                     0, stream, x, y, ws);
  hipLaunchKernelGGL(finalize_kernel, dim3(1), dim3(256), 0, stream, ws + 256, out);
}